// Round 1
// baseline (2756.033 us; speedup 1.0000x reference)
//
#include <hip/hip_runtime.h>

// ---------------------------------------------------------------------------
// SelfAttention (B=8, C=512, T=4096, DK=64):
//   sigma = spectral norm of Wv (1 power iter); val = (Wv x)/sigma + bv
//   q = Wq x, k = Wk x; attn = softmax(q^T k / 8); out = val @ attn^T + x
// Pipeline: sigma_kernel -> qkproj -> valproj -> flash attention (bf16 MFMA)
// Workspace: 1KB (sigma) + 4MB Q + 4MB K + 32MB V  (~41MB)
// ---------------------------------------------------------------------------

#define B_  8
#define C_  512
#define T_  4096
#define DK_ 64

typedef __bf16 bf16x8 __attribute__((ext_vector_type(8)));
typedef float  f32x4  __attribute__((ext_vector_type(4)));

static __device__ __forceinline__ unsigned short f2bf(float f) {
  unsigned u = __float_as_uint(f);
  u += 0x7fffu + ((u >> 16) & 1u);
  return (unsigned short)(u >> 16);
}

// ---------------------------------------------------------------------------
// Kernel 1: spectral norm -> inv_sigma
// ---------------------------------------------------------------------------
__global__ void sigma_kernel(const float* __restrict__ Wv,
                             const float* __restrict__ u,
                             float* __restrict__ sig) {
  __shared__ float red[512];
  __shared__ float vsh[512];
  __shared__ float snorm;
  int tid = threadIdx.x;  // 512 threads

  vsh[tid] = u[tid];
  __syncthreads();
  // v_raw[c] = sum_j Wv[j][c] * u[j]   (coalesced over c)
  float acc = 0.f;
  for (int j = 0; j < 512; ++j) acc += Wv[(size_t)j * 512 + tid] * vsh[j];
  red[tid] = acc * acc;
  __syncthreads();
  for (int s = 256; s >= 1; s >>= 1) {
    if (tid < s) red[tid] += red[tid + s];
    __syncthreads();
  }
  if (tid == 0) snorm = sqrtf(red[0]) + 1e-12f;
  __syncthreads();
  float v = acc / snorm;
  __syncthreads();           // everyone done reading vsh (held u)
  vsh[tid] = v;
  __syncthreads();
  // w[j] = sum_c Wv[j][c] * v[c]   (row per thread; L2-hot)
  float wacc = 0.f;
  for (int c = 0; c < 512; ++c) wacc += Wv[(size_t)tid * 512 + c] * vsh[c];
  red[tid] = wacc * wacc;
  __syncthreads();
  for (int s = 256; s >= 1; s >>= 1) {
    if (tid < s) red[tid] += red[tid + s];
    __syncthreads();
  }
  if (tid == 0) {
    float ww = red[0];                       // ||w||^2
    float sigma = ww / (sqrtf(ww) + 1e-12f); // u2 . (Wv v)
    sig[0] = 1.f / sigma;
  }
}

// ---------------------------------------------------------------------------
// Kernel 2: Q/K projection.  Q[b][t][d] bf16 (scaled by log2e/8), K[b][t][d].
// grid (T/64, B), 256 threads. Thread: t = t0 + tid&63, o-group g = tid>>6
// owns 32 of 128 outputs (o<64 -> q, else k). W staged in LDS per c-chunk.
// ---------------------------------------------------------------------------
__global__ __launch_bounds__(256)
void qkproj_kernel(const float* __restrict__ Wq, const float* __restrict__ Wk,
                   const float* __restrict__ x,
                   unsigned short* __restrict__ Q,
                   unsigned short* __restrict__ Kk) {
  __shared__ __align__(16) float wlds[128][64];
  int tid = threadIdx.x;
  int t = blockIdx.x * 64 + (tid & 63);
  int b = blockIdx.y;
  int g = tid >> 6;
  const float* xb = x + (size_t)b * C_ * T_;

  float acc[32];
#pragma unroll
  for (int i = 0; i < 32; ++i) acc[i] = 0.f;

  for (int cc = 0; cc < 512; cc += 64) {
#pragma unroll
    for (int k2 = 0; k2 < 32; ++k2) {
      int idx = k2 * 256 + tid;
      int o = idx >> 6, c = idx & 63;
      wlds[o][c] = (o < 64) ? Wq[(size_t)o * 512 + cc + c]
                            : Wk[(size_t)(o - 64) * 512 + cc + c];
    }
    __syncthreads();
    for (int c4 = 0; c4 < 64; c4 += 4) {
      float x0 = xb[(size_t)(cc + c4 + 0) * T_ + t];
      float x1 = xb[(size_t)(cc + c4 + 1) * T_ + t];
      float x2 = xb[(size_t)(cc + c4 + 2) * T_ + t];
      float x3 = xb[(size_t)(cc + c4 + 3) * T_ + t];
#pragma unroll
      for (int i = 0; i < 32; ++i) {
        float4 w4 = *reinterpret_cast<const float4*>(&wlds[g * 32 + i][c4]);
        acc[i] = fmaf(w4.x, x0, fmaf(w4.y, x1, fmaf(w4.z, x2, fmaf(w4.w, x3, acc[i]))));
      }
    }
    __syncthreads();
  }

  const float QSCALE = 1.4426950408889634f / 8.0f;  // log2(e)/SCALE folded into Q
#pragma unroll
  for (int i = 0; i < 32; ++i) {
    int o = g * 32 + i;
    if (o < 64)
      Q[((size_t)b * T_ + t) * DK_ + o] = f2bf(acc[i] * QSCALE);
    else
      Kk[((size_t)b * T_ + t) * DK_ + (o - 64)] = f2bf(acc[i]);
  }
}

// ---------------------------------------------------------------------------
// Kernel 3: val projection. V[b][c][t] bf16 = (Wv x)*inv_sigma + bv.
// grid (T/64, 4 o-chunks of 128, B), 256 threads.
// ---------------------------------------------------------------------------
__global__ __launch_bounds__(256)
void valproj_kernel(const float* __restrict__ Wv, const float* __restrict__ bv,
                    const float* __restrict__ x, const float* __restrict__ sig,
                    unsigned short* __restrict__ V) {
  __shared__ __align__(16) float wlds[128][64];
  int tid = threadIdx.x;
  int t = blockIdx.x * 64 + (tid & 63);
  int oc = blockIdx.y;  // 0..3
  int b = blockIdx.z;
  int g = tid >> 6;
  float inv_sigma = sig[0];
  const float* xb = x + (size_t)b * C_ * T_;

  float acc[32];
#pragma unroll
  for (int i = 0; i < 32; ++i) acc[i] = 0.f;

  for (int cc = 0; cc < 512; cc += 64) {
#pragma unroll
    for (int k2 = 0; k2 < 32; ++k2) {
      int idx = k2 * 256 + tid;
      int o = idx >> 6, c = idx & 63;
      wlds[o][c] = Wv[(size_t)(oc * 128 + o) * 512 + cc + c];
    }
    __syncthreads();
    for (int c4 = 0; c4 < 64; c4 += 4) {
      float x0 = xb[(size_t)(cc + c4 + 0) * T_ + t];
      float x1 = xb[(size_t)(cc + c4 + 1) * T_ + t];
      float x2 = xb[(size_t)(cc + c4 + 2) * T_ + t];
      float x3 = xb[(size_t)(cc + c4 + 3) * T_ + t];
#pragma unroll
      for (int i = 0; i < 32; ++i) {
        float4 w4 = *reinterpret_cast<const float4*>(&wlds[g * 32 + i][c4]);
        acc[i] = fmaf(w4.x, x0, fmaf(w4.y, x1, fmaf(w4.z, x2, fmaf(w4.w, x3, acc[i]))));
      }
    }
    __syncthreads();
  }

#pragma unroll
  for (int i = 0; i < 32; ++i) {
    int c_out = oc * 128 + g * 32 + i;
    float v = acc[i] * inv_sigma + bv[c_out];
    V[((size_t)b * C_ + c_out) * T_ + t] = f2bf(v);
  }
}

// ---------------------------------------------------------------------------
// Kernel 4: flash attention + residual.
// grid (T/64, B), 256 threads = 4 waves. Wave w owns q-rows t0+16w..+16,
// all 512 output channels. 16x16x32 bf16 MFMA.
//  A-frag (row=lane&15, k=(lane>>4)*8+i):  Q rows / P rows (LDS, swizzled)
//  B-frag (col=lane&15, k=(lane>>4)*8+i):  K rows / V rows, direct global
//  C/D   (col=lane&15, row=(lane>>4)*4+r)  [verified layout]
// ---------------------------------------------------------------------------
__global__ __launch_bounds__(256, 2)
void flash_kernel(const unsigned short* __restrict__ Q,
                  const unsigned short* __restrict__ Kk,
                  const unsigned short* __restrict__ V,
                  const float* __restrict__ x, float* __restrict__ out) {
  __shared__ __align__(16) unsigned short p_lds[4][16 * 64];  // per-wave 2KB

  int tid = threadIdx.x;
  int w = tid >> 6;
  int lane = tid & 63;
  int col = lane & 15;   // frag row/col selector
  int g = lane >> 4;     // k-group / acc row group
  int b = blockIdx.y;
  int t0 = blockIdx.x * 64;
  int trow0 = t0 + w * 16;

  const unsigned short* Qb = Q + (size_t)b * T_ * DK_;
  const unsigned short* Kb = Kk + (size_t)b * T_ * DK_;
  const unsigned short* Vb = V + (size_t)b * C_ * T_;

  // Q A-fragments (K=64 -> 2 k-steps), live in registers for whole kernel
  bf16x8 qf[2];
  {
    const unsigned short* qrow = Qb + (size_t)(trow0 + col) * DK_ + g * 8;
    qf[0] = *reinterpret_cast<const bf16x8*>(qrow);
    qf[1] = *reinterpret_cast<const bf16x8*>(qrow + 32);
  }

  float m_r[4], l_r[4];
  f32x4 o_acc[32];
#pragma unroll
  for (int n = 0; n < 32; ++n) o_acc[n] = (f32x4){0.f, 0.f, 0.f, 0.f};
#pragma unroll
  for (int r = 0; r < 4; ++r) { m_r[r] = -1e30f; l_r[r] = 0.f; }

  for (int s0 = 0; s0 < T_; s0 += 64) {
    // ---- S = Q K^T (pre-scaled by log2e/8 via Q) ----
    f32x4 sacc[4];
#pragma unroll
    for (int j = 0; j < 4; ++j) sacc[j] = (f32x4){0.f, 0.f, 0.f, 0.f};
#pragma unroll
    for (int ks = 0; ks < 2; ++ks) {
      const unsigned short* kbase = Kb + (size_t)(s0 + col) * DK_ + 32 * ks + g * 8;
#pragma unroll
      for (int j = 0; j < 4; ++j) {
        bf16x8 kf = *reinterpret_cast<const bf16x8*>(kbase + (size_t)j * 16 * DK_);
        sacc[j] = __builtin_amdgcn_mfma_f32_16x16x32_bf16(qf[ks], kf, sacc[j], 0, 0, 0);
      }
    }
    // ---- online softmax (rows wave-local: row = g*4+r, cols = lane&15 + 16j)
    float scale_f[4];
#pragma unroll
    for (int r = 0; r < 4; ++r) {
      float mx = fmaxf(fmaxf(sacc[0][r], sacc[1][r]), fmaxf(sacc[2][r], sacc[3][r]));
      mx = fmaxf(mx, __shfl_xor(mx, 1));
      mx = fmaxf(mx, __shfl_xor(mx, 2));
      mx = fmaxf(mx, __shfl_xor(mx, 4));
      mx = fmaxf(mx, __shfl_xor(mx, 8));
      float mnew = fmaxf(m_r[r], mx);
      scale_f[r] = exp2f(m_r[r] - mnew);
      float rs = 0.f;
#pragma unroll
      for (int j = 0; j < 4; ++j) {
        float p = exp2f(sacc[j][r] - mnew);
        sacc[j][r] = p;
        rs += p;
      }
      rs += __shfl_xor(rs, 1);
      rs += __shfl_xor(rs, 2);
      rs += __shfl_xor(rs, 4);
      rs += __shfl_xor(rs, 8);
      l_r[r] = l_r[r] * scale_f[r] + rs;
      m_r[r] = mnew;
    }
    // ---- P -> LDS (bf16, XOR-swizzled rows to kill b128 read conflicts) ----
#pragma unroll
    for (int j = 0; j < 4; ++j)
#pragma unroll
      for (int r = 0; r < 4; ++r) {
        int row = g * 4 + r;
        int byteoff = (row * 128 + (16 * j + col) * 2) ^ ((row & 7) << 4);
        *(unsigned short*)((char*)p_lds[w] + byteoff) = f2bf(sacc[j][r]);
      }
    __syncthreads();
    // ---- rescale O ----
#pragma unroll
    for (int n = 0; n < 32; ++n) {
      o_acc[n][0] *= scale_f[0];
      o_acc[n][1] *= scale_f[1];
      o_acc[n][2] *= scale_f[2];
      o_acc[n][3] *= scale_f[3];
    }
    // ---- O += P V  (V frags direct from global, k-contiguous) ----
#pragma unroll
    for (int ks = 0; ks < 2; ++ks) {
      int row = col;  // A-frag row = t-local
      int bo = (row * 128 + 64 * ks + g * 16) ^ ((row & 7) << 4);
      bf16x8 pf = *reinterpret_cast<const bf16x8*>((char*)p_lds[w] + bo);
      const unsigned short* vbase = Vb + (size_t)col * T_ + s0 + 32 * ks + g * 8;
#pragma unroll
      for (int n = 0; n < 32; ++n) {
        bf16x8 vf = *reinterpret_cast<const bf16x8*>(vbase + (size_t)n * 16 * T_);
        o_acc[n] = __builtin_amdgcn_mfma_f32_16x16x32_bf16(pf, vf, o_acc[n], 0, 0, 0);
      }
    }
    __syncthreads();  // protect p_lds before next tile overwrites
  }

  // ---- epilogue: out = O/l + x ----
  const float* xb = x + (size_t)b * C_ * T_;
  float* ob = out + (size_t)b * C_ * T_;
  float inv_l[4];
#pragma unroll
  for (int r = 0; r < 4; ++r) inv_l[r] = 1.f / l_r[r];
#pragma unroll
  for (int n = 0; n < 32; ++n) {
    int c = 16 * n + col;
#pragma unroll
    for (int r = 0; r < 4; ++r) {
      int t = trow0 + g * 4 + r;
      size_t idx = (size_t)c * T_ + t;
      ob[idx] = o_acc[n][r] * inv_l[r] + xb[idx];
    }
  }
}

// ---------------------------------------------------------------------------
extern "C" void kernel_launch(void* const* d_in, const int* in_sizes, int n_in,
                              void* d_out, int out_size, void* d_ws, size_t ws_size,
                              hipStream_t stream) {
  const float* x  = (const float*)d_in[0];
  const float* Wq = (const float*)d_in[1];
  const float* Wk = (const float*)d_in[2];
  const float* Wv = (const float*)d_in[3];
  const float* bv = (const float*)d_in[4];
  const float* u  = (const float*)d_in[5];
  float* out = (float*)d_out;

  float* sig = (float*)d_ws;
  unsigned short* Q  = (unsigned short*)((char*)d_ws + 1024);
  unsigned short* Kk = Q + (size_t)B_ * T_ * DK_;            // +4MB
  unsigned short* V  = Kk + (size_t)B_ * T_ * DK_;           // +4MB (V is 32MB)

  sigma_kernel<<<1, 512, 0, stream>>>(Wv, u, sig);
  qkproj_kernel<<<dim3(T_ / 64, B_), 256, 0, stream>>>(Wq, Wk, x, Q, Kk);
  valproj_kernel<<<dim3(T_ / 64, 4, B_), 256, 0, stream>>>(Wv, bv, x, sig, V);
  flash_kernel<<<dim3(T_ / 64, B_), 256, 0, stream>>>(Q, Kk, V, x, out);
}

// Round 2
// 1055.815 us; speedup vs baseline: 2.6103x; 2.6103x over previous
//
#include <hip/hip_runtime.h>

// ---------------------------------------------------------------------------
// SelfAttention (B=8, C=512, T=4096, DK=64):
//   sigma = spectral norm of Wv (1 power iter); val = (Wv x)/sigma + bv
//   q = Wq x, k = Wk x; attn = softmax(q^T k / 8); out = val @ attn^T + x
// Pipeline: sigma_kernel -> qkproj -> valproj -> flash attention (bf16 MFMA)
// flash: 8-wave blocks of 128 q-rows, V tile double-buffered in LDS via
// global_load_lds (pre-swizzled source), XCD-pinned batches, transposed
// epilogue, defer-rescale online softmax.
// ---------------------------------------------------------------------------

#define B_  8
#define C_  512
#define T_  4096
#define DK_ 64

typedef __bf16 bf16x8 __attribute__((ext_vector_type(8)));
typedef float  f32x4  __attribute__((ext_vector_type(4)));

static __device__ __forceinline__ unsigned short f2bf(float f) {
  unsigned u = __float_as_uint(f);
  u += 0x7fffu + ((u >> 16) & 1u);
  return (unsigned short)(u >> 16);
}

// ---------------------------------------------------------------------------
// Kernel 1: spectral norm -> inv_sigma
// ---------------------------------------------------------------------------
__global__ void sigma_kernel(const float* __restrict__ Wv,
                             const float* __restrict__ u,
                             float* __restrict__ sig) {
  __shared__ float red[512];
  __shared__ float vsh[512];
  __shared__ float snorm;
  int tid = threadIdx.x;  // 512 threads

  vsh[tid] = u[tid];
  __syncthreads();
  float acc = 0.f;
  for (int j = 0; j < 512; ++j) acc += Wv[(size_t)j * 512 + tid] * vsh[j];
  red[tid] = acc * acc;
  __syncthreads();
  for (int s = 256; s >= 1; s >>= 1) {
    if (tid < s) red[tid] += red[tid + s];
    __syncthreads();
  }
  if (tid == 0) snorm = sqrtf(red[0]) + 1e-12f;
  __syncthreads();
  float v = acc / snorm;
  __syncthreads();
  vsh[tid] = v;
  __syncthreads();
  float wacc = 0.f;
  for (int c = 0; c < 512; ++c) wacc += Wv[(size_t)tid * 512 + c] * vsh[c];
  red[tid] = wacc * wacc;
  __syncthreads();
  for (int s = 256; s >= 1; s >>= 1) {
    if (tid < s) red[tid] += red[tid + s];
    __syncthreads();
  }
  if (tid == 0) {
    float ww = red[0];
    float sigma = ww / (sqrtf(ww) + 1e-12f);
    sig[0] = 1.f / sigma;
  }
}

// ---------------------------------------------------------------------------
// Kernel 2: Q/K projection.  Q[b][t][d] bf16 (scaled by log2e/8), K[b][t][d].
// ---------------------------------------------------------------------------
__global__ __launch_bounds__(256)
void qkproj_kernel(const float* __restrict__ Wq, const float* __restrict__ Wk,
                   const float* __restrict__ x,
                   unsigned short* __restrict__ Q,
                   unsigned short* __restrict__ Kk) {
  __shared__ __align__(16) float wlds[128][64];
  int tid = threadIdx.x;
  int t = blockIdx.x * 64 + (tid & 63);
  int b = blockIdx.y;
  int g = tid >> 6;
  const float* xb = x + (size_t)b * C_ * T_;

  float acc[32];
#pragma unroll
  for (int i = 0; i < 32; ++i) acc[i] = 0.f;

  for (int cc = 0; cc < 512; cc += 64) {
#pragma unroll
    for (int k2 = 0; k2 < 32; ++k2) {
      int idx = k2 * 256 + tid;
      int o = idx >> 6, c = idx & 63;
      wlds[o][c] = (o < 64) ? Wq[(size_t)o * 512 + cc + c]
                            : Wk[(size_t)(o - 64) * 512 + cc + c];
    }
    __syncthreads();
    for (int c4 = 0; c4 < 64; c4 += 4) {
      float x0 = xb[(size_t)(cc + c4 + 0) * T_ + t];
      float x1 = xb[(size_t)(cc + c4 + 1) * T_ + t];
      float x2 = xb[(size_t)(cc + c4 + 2) * T_ + t];
      float x3 = xb[(size_t)(cc + c4 + 3) * T_ + t];
#pragma unroll
      for (int i = 0; i < 32; ++i) {
        float4 w4 = *reinterpret_cast<const float4*>(&wlds[g * 32 + i][c4]);
        acc[i] = fmaf(w4.x, x0, fmaf(w4.y, x1, fmaf(w4.z, x2, fmaf(w4.w, x3, acc[i]))));
      }
    }
    __syncthreads();
  }

  const float QSCALE = 1.4426950408889634f / 8.0f;
#pragma unroll
  for (int i = 0; i < 32; ++i) {
    int o = g * 32 + i;
    if (o < 64)
      Q[((size_t)b * T_ + t) * DK_ + o] = f2bf(acc[i] * QSCALE);
    else
      Kk[((size_t)b * T_ + t) * DK_ + (o - 64)] = f2bf(acc[i]);
  }
}

// ---------------------------------------------------------------------------
// Kernel 3: val projection. V[b][c][t] bf16 = (Wv x)*inv_sigma + bv.
// ---------------------------------------------------------------------------
__global__ __launch_bounds__(256)
void valproj_kernel(const float* __restrict__ Wv, const float* __restrict__ bv,
                    const float* __restrict__ x, const float* __restrict__ sig,
                    unsigned short* __restrict__ V) {
  __shared__ __align__(16) float wlds[128][64];
  int tid = threadIdx.x;
  int t = blockIdx.x * 64 + (tid & 63);
  int oc = blockIdx.y;  // 0..3
  int b = blockIdx.z;
  int g = tid >> 6;
  float inv_sigma = sig[0];
  const float* xb = x + (size_t)b * C_ * T_;

  float acc[32];
#pragma unroll
  for (int i = 0; i < 32; ++i) acc[i] = 0.f;

  for (int cc = 0; cc < 512; cc += 64) {
#pragma unroll
    for (int k2 = 0; k2 < 32; ++k2) {
      int idx = k2 * 256 + tid;
      int o = idx >> 6, c = idx & 63;
      wlds[o][c] = Wv[(size_t)(oc * 128 + o) * 512 + cc + c];
    }
    __syncthreads();
    for (int c4 = 0; c4 < 64; c4 += 4) {
      float x0 = xb[(size_t)(cc + c4 + 0) * T_ + t];
      float x1 = xb[(size_t)(cc + c4 + 1) * T_ + t];
      float x2 = xb[(size_t)(cc + c4 + 2) * T_ + t];
      float x3 = xb[(size_t)(cc + c4 + 3) * T_ + t];
#pragma unroll
      for (int i = 0; i < 32; ++i) {
        float4 w4 = *reinterpret_cast<const float4*>(&wlds[g * 32 + i][c4]);
        acc[i] = fmaf(w4.x, x0, fmaf(w4.y, x1, fmaf(w4.z, x2, fmaf(w4.w, x3, acc[i]))));
      }
    }
    __syncthreads();
  }

#pragma unroll
  for (int i = 0; i < 32; ++i) {
    int c_out = oc * 128 + g * 32 + i;
    float v = acc[i] * inv_sigma + bv[c_out];
    V[((size_t)b * C_ + c_out) * T_ + t] = f2bf(v);
  }
}

// ---------------------------------------------------------------------------
// Kernel 4: flash attention + residual.
// grid 256 blocks (1/CU): b = bid&7 (XCD-pinned), t0 = (bid>>3)*128.
// 512 threads = 8 waves; wave w owns q-rows t0+16w..+16, all 512 channels.
// V tile (512c x 64s bf16, 64KB) double-buffered in LDS via global_load_lds
// with pre-swizzled source (byte ^ ((c&7)<<4)); 2-phase pipeline, one
// vmcnt(0)+barrier per tile (inside __syncthreads).
// ---------------------------------------------------------------------------
__global__ __launch_bounds__(512, 2)
void flash_kernel(const unsigned short* __restrict__ Q,
                  const unsigned short* __restrict__ Kk,
                  const unsigned short* __restrict__ V,
                  const float* __restrict__ x, float* __restrict__ out) {
  __shared__ __align__(16) unsigned short v_lds[2][C_ * 64];  // 2 x 64KB
  __shared__ __align__(16) unsigned short p_lds[8][16 * 64];  // 8 x 2KB

  const int tid = threadIdx.x;
  const int w = tid >> 6;
  const int lane = tid & 63;
  const int col = lane & 15;
  const int g = lane >> 4;
  const int bid = blockIdx.x;
  const int b = bid & 7;               // batch == XCD slot (L2 locality)
  const int t0 = (bid >> 3) * 128;
  const int trow0 = t0 + w * 16;

  const unsigned short* Qb = Q + (size_t)b * T_ * DK_;
  const unsigned short* Kb = Kk + (size_t)b * T_ * DK_;
  const unsigned short* Vb = V + (size_t)b * C_ * T_;

  // ---- stage one V tile (s0..s0+64) into v_lds[bsel], swizzled layout ----
  auto stage = [&](int bsel, int s0) {
#pragma unroll
    for (int i = 0; i < 8; ++i) {
      int o = i * 8192 + tid * 16;               // linear LDS byte offset
      int c = o >> 7;                            // V row
      int z = (o & 127) ^ ((c & 7) << 4);        // pre-swizzled source byte
      const unsigned short* src = Vb + (size_t)c * T_ + s0 + (z >> 1);
      void* dst = (char*)(&v_lds[bsel][0]) + i * 8192 + w * 1024;  // wave-uniform
      __builtin_amdgcn_global_load_lds(
          (const __attribute__((address_space(1))) unsigned int*)src,
          (__attribute__((address_space(3))) unsigned int*)dst, 16, 0, 0);
    }
  };

  // Q A-fragments (K=64 -> 2 k-steps), in registers for whole kernel
  bf16x8 qf[2];
  {
    const unsigned short* qrow = Qb + (size_t)(trow0 + col) * DK_ + g * 8;
    qf[0] = *reinterpret_cast<const bf16x8*>(qrow);
    qf[1] = *reinterpret_cast<const bf16x8*>(qrow + 32);
  }

  // K B-fragments for current tile (prefetched across the barrier)
  bf16x8 kf[2][4];
  auto loadK = [&](int s0) {
#pragma unroll
    for (int ks = 0; ks < 2; ++ks)
#pragma unroll
      for (int j = 0; j < 4; ++j)
        kf[ks][j] = *reinterpret_cast<const bf16x8*>(
            Kb + (size_t)(s0 + col + 16 * j) * DK_ + 32 * ks + g * 8);
  };

  float m_r[4], l_r[4];
  f32x4 o_acc[32];
#pragma unroll
  for (int n = 0; n < 32; ++n) o_acc[n] = (f32x4){0.f, 0.f, 0.f, 0.f};
#pragma unroll
  for (int r = 0; r < 4; ++r) { m_r[r] = -1e30f; l_r[r] = 0.f; }

  stage(0, 0);
  loadK(0);
  __syncthreads();  // drains vmcnt(0): tile 0 + K 0 resident
  int cur = 0;

  const float RTHR = 10.0f;  // defer-rescale threshold (log2 domain)

  for (int it = 0; it < T_ / 64; ++it) {
    const int s0 = it * 64;
    if (it + 1 < T_ / 64) stage(cur ^ 1, s0 + 64);  // async prefetch next tile

    // ---- S = Q K^T (pre-scaled by log2e/8 via Q) ----
    f32x4 sacc[4];
#pragma unroll
    for (int j = 0; j < 4; ++j) sacc[j] = (f32x4){0.f, 0.f, 0.f, 0.f};
#pragma unroll
    for (int ks = 0; ks < 2; ++ks)
#pragma unroll
      for (int j = 0; j < 4; ++j)
        sacc[j] = __builtin_amdgcn_mfma_f32_16x16x32_bf16(qf[ks], kf[ks][j], sacc[j], 0, 0, 0);

    // ---- online softmax with defer-rescale ----
    float mx[4];
#pragma unroll
    for (int r = 0; r < 4; ++r) {
      float m2 = fmaxf(fmaxf(sacc[0][r], sacc[1][r]), fmaxf(sacc[2][r], sacc[3][r]));
      m2 = fmaxf(m2, __shfl_xor(m2, 1));
      m2 = fmaxf(m2, __shfl_xor(m2, 2));
      m2 = fmaxf(m2, __shfl_xor(m2, 4));
      m2 = fmaxf(m2, __shfl_xor(m2, 8));
      mx[r] = m2;
    }
    int ok = (mx[0] <= m_r[0] + RTHR) && (mx[1] <= m_r[1] + RTHR) &&
             (mx[2] <= m_r[2] + RTHR) && (mx[3] <= m_r[3] + RTHR);
    if (!__all(ok)) {
      float scl[4];
#pragma unroll
      for (int r = 0; r < 4; ++r) {
        float mnew = fmaxf(m_r[r], mx[r]);
        scl[r] = exp2f(m_r[r] - mnew);
        m_r[r] = mnew;
        l_r[r] *= scl[r];
      }
#pragma unroll
      for (int n = 0; n < 32; ++n) {
        o_acc[n][0] *= scl[0];
        o_acc[n][1] *= scl[1];
        o_acc[n][2] *= scl[2];
        o_acc[n][3] *= scl[3];
      }
    }
#pragma unroll
    for (int r = 0; r < 4; ++r) {
      float rs = 0.f;
#pragma unroll
      for (int j = 0; j < 4; ++j) {
        float p = exp2f(sacc[j][r] - m_r[r]);
        sacc[j][r] = p;
        rs += p;
      }
      rs += __shfl_xor(rs, 1);
      rs += __shfl_xor(rs, 2);
      rs += __shfl_xor(rs, 4);
      rs += __shfl_xor(rs, 8);
      l_r[r] += rs;
    }

    // ---- P -> LDS (bf16, XOR-swizzled; wave-private, no barrier) ----
#pragma unroll
    for (int j = 0; j < 4; ++j)
#pragma unroll
      for (int r = 0; r < 4; ++r) {
        int row = g * 4 + r;
        int byteoff = (row * 128 + (16 * j + col) * 2) ^ ((row & 7) << 4);
        *(unsigned short*)((char*)p_lds[w] + byteoff) = f2bf(sacc[j][r]);
      }

    // ---- O += P V  (V B-frags from swizzled LDS) ----
#pragma unroll
    for (int ks = 0; ks < 2; ++ks) {
      int bo = (col * 128 + 64 * ks + 16 * g) ^ ((col & 7) << 4);
      bf16x8 pf = *reinterpret_cast<const bf16x8*>((char*)p_lds[w] + bo);
      int zv = (64 * ks + 16 * g) ^ ((col & 7) << 4);
      const char* vb0 = (const char*)v_lds[cur] + col * 128 + zv;
#pragma unroll
      for (int n = 0; n < 32; ++n) {
        bf16x8 vf = *reinterpret_cast<const bf16x8*>(vb0 + n * 2048);
        o_acc[n] = __builtin_amdgcn_mfma_f32_16x16x32_bf16(pf, vf, o_acc[n], 0, 0, 0);
      }
    }

    if (it + 1 < T_ / 64) loadK(s0 + 64);  // K prefetch drains at the barrier
    __syncthreads();  // vmcnt(0)+lgkmcnt(0)+barrier: next tile ready, buf safe
    cur ^= 1;
  }

  // ---- epilogue: transpose O via LDS, coalesced out = O/l + x ----
  float inv_l[4];
#pragma unroll
  for (int r = 0; r < 4; ++r) inv_l[r] = 1.f / l_r[r];
  const float* xb = x + (size_t)b * C_ * T_;
  float* ob = out + (size_t)b * C_ * T_;
  float* scratch = (float*)((char*)v_lds + (size_t)w * 16384);  // 16KB/wave

#pragma unroll
  for (int ch = 0; ch < 4; ++ch) {
#pragma unroll
    for (int nn = 0; nn < 8; ++nn) {
      int n = ch * 8 + nn;
      int c_local = nn * 16 + col;
#pragma unroll
      for (int r = 0; r < 4; ++r)
        scratch[c_local * 17 + g * 4 + r] = o_acc[n][r] * inv_l[r];
    }
    // read back transposed: lane -> (c_local = i*4+g, t_local = col)
#pragma unroll
    for (int i = 0; i < 32; ++i) {
      int c_local = i * 4 + g;
      float v = scratch[c_local * 17 + col];
      size_t idx = (size_t)(ch * 128 + c_local) * T_ + trow0 + col;
      ob[idx] = v + xb[idx];
    }
  }
}

// ---------------------------------------------------------------------------
extern "C" void kernel_launch(void* const* d_in, const int* in_sizes, int n_in,
                              void* d_out, int out_size, void* d_ws, size_t ws_size,
                              hipStream_t stream) {
  const float* x  = (const float*)d_in[0];
  const float* Wq = (const float*)d_in[1];
  const float* Wk = (const float*)d_in[2];
  const float* Wv = (const float*)d_in[3];
  const float* bv = (const float*)d_in[4];
  const float* u  = (const float*)d_in[5];
  float* out = (float*)d_out;

  float* sig = (float*)d_ws;
  unsigned short* Q  = (unsigned short*)((char*)d_ws + 1024);
  unsigned short* Kk = Q + (size_t)B_ * T_ * DK_;            // +4MB
  unsigned short* V  = Kk + (size_t)B_ * T_ * DK_;           // +4MB (V is 32MB)

  sigma_kernel<<<1, 512, 0, stream>>>(Wv, u, sig);
  qkproj_kernel<<<dim3(T_ / 64, B_), 256, 0, stream>>>(Wq, Wk, x, Q, Kk);
  valproj_kernel<<<dim3(T_ / 64, 4, B_), 256, 0, stream>>>(Wv, bv, x, sig, V);
  flash_kernel<<<dim3(256), 512, 0, stream>>>(Q, Kk, V, x, out);
}

// Round 3
// 369.449 us; speedup vs baseline: 7.4599x; 2.8578x over previous
//
#include <hip/hip_runtime.h>

// ---------------------------------------------------------------------------
// SelfAttention (B=8, C=512, T=4096, DK=64):
//   sigma = spectral norm of Wv (1 power iter); val = (Wv x)/sigma + bv
//   q = Wq x, k = Wk x; attn = softmax(q^T k / 8); out = val @ attn^T + x
// Pipeline:
//   sigma  -> inv_sigma
//   castw  -> Wc[640][512] bf16 = [Wq*log2e/8 ; Wk ; Wv/sigma]
//   castt  -> xT[b][t][c] bf16 (LDS transpose)
//   proj   -> unified MFMA GEMM: Q[t][d], K[t][d], V[c][t] (+bv)
//   flash  -> flash attention (bf16 MFMA) + residual
// Workspace: sig 1KB | Q 4MB | K 4MB | V 32MB | xT 32MB | Wc 640KB  (~73MB)
// ---------------------------------------------------------------------------

#define B_  8
#define C_  512
#define T_  4096
#define DK_ 64

typedef __bf16 bf16x8 __attribute__((ext_vector_type(8)));
typedef float  f32x4  __attribute__((ext_vector_type(4)));

static __device__ __forceinline__ unsigned short f2bf(float f) {
  unsigned u = __float_as_uint(f);
  u += 0x7fffu + ((u >> 16) & 1u);
  return (unsigned short)(u >> 16);
}

// ---------------------------------------------------------------------------
// Kernel 1: spectral norm -> inv_sigma
// ---------------------------------------------------------------------------
__global__ void sigma_kernel(const float* __restrict__ Wv,
                             const float* __restrict__ u,
                             float* __restrict__ sig) {
  __shared__ float red[512];
  __shared__ float vsh[512];
  __shared__ float snorm;
  int tid = threadIdx.x;  // 512 threads

  vsh[tid] = u[tid];
  __syncthreads();
  float acc = 0.f;
  for (int j = 0; j < 512; ++j) acc += Wv[(size_t)j * 512 + tid] * vsh[j];
  red[tid] = acc * acc;
  __syncthreads();
  for (int s = 256; s >= 1; s >>= 1) {
    if (tid < s) red[tid] += red[tid + s];
    __syncthreads();
  }
  if (tid == 0) snorm = sqrtf(red[0]) + 1e-12f;
  __syncthreads();
  float v = acc / snorm;
  __syncthreads();
  vsh[tid] = v;
  __syncthreads();
  float wacc = 0.f;
  for (int c = 0; c < 512; ++c) wacc += Wv[(size_t)tid * 512 + c] * vsh[c];
  red[tid] = wacc * wacc;
  __syncthreads();
  for (int s = 256; s >= 1; s >>= 1) {
    if (tid < s) red[tid] += red[tid + s];
    __syncthreads();
  }
  if (tid == 0) {
    float ww = red[0];
    float sigma = ww / (sqrtf(ww) + 1e-12f);
    sig[0] = 1.f / sigma;
  }
}

// ---------------------------------------------------------------------------
// Kernel 2: stack + scale weights to bf16: Wc[640][512]
//   rows 0..63  = Wq * (log2e/8)   (QK^T scale folded)
//   rows 64..127= Wk
//   rows 128+   = Wv * inv_sigma
// ---------------------------------------------------------------------------
__global__ __launch_bounds__(128)
void castw_kernel(const float* __restrict__ Wq, const float* __restrict__ Wk,
                  const float* __restrict__ Wv, const float* __restrict__ sig,
                  unsigned short* __restrict__ Wc) {
  int row = blockIdx.x;
  int c = threadIdx.x * 4;
  const float* src;
  float s;
  if (row < 64) {
    src = Wq + (size_t)row * 512;
    s = 1.4426950408889634f / 8.0f;
  } else if (row < 128) {
    src = Wk + (size_t)(row - 64) * 512;
    s = 1.0f;
  } else {
    src = Wv + (size_t)(row - 128) * 512;
    s = sig[0];
  }
  float4 v = *reinterpret_cast<const float4*>(src + c);
  ushort4 o;
  o.x = f2bf(v.x * s);
  o.y = f2bf(v.y * s);
  o.z = f2bf(v.z * s);
  o.w = f2bf(v.w * s);
  *reinterpret_cast<ushort4*>(Wc + (size_t)row * 512 + c) = o;
}

// ---------------------------------------------------------------------------
// Kernel 3: transpose-cast x[b][c][t] f32 -> xT[b][t][c] bf16.
// grid (T/64, C/64, B), 256 threads, 64x64 tile via LDS.
// ---------------------------------------------------------------------------
__global__ __launch_bounds__(256)
void castt_kernel(const float* __restrict__ x, unsigned short* __restrict__ xT) {
  __shared__ __align__(16) unsigned short ldsT[64][72];  // [t][c], +8 pad
  int tid = threadIdx.x;
  int t0 = blockIdx.x * 64, c0 = blockIdx.y * 64, b = blockIdx.z;
  const float* xb = x + ((size_t)b * C_ + c0) * T_ + t0;
#pragma unroll
  for (int k2 = 0; k2 < 4; ++k2) {
    int idx = k2 * 256 + tid;
    int c = idx >> 4, t4 = (idx & 15) * 4;
    float4 v = *reinterpret_cast<const float4*>(xb + (size_t)c * T_ + t4);
    ldsT[t4 + 0][c] = f2bf(v.x);
    ldsT[t4 + 1][c] = f2bf(v.y);
    ldsT[t4 + 2][c] = f2bf(v.z);
    ldsT[t4 + 3][c] = f2bf(v.w);
  }
  __syncthreads();
  unsigned short* xTb = xT + ((size_t)b * T_ + t0) * C_ + c0;
#pragma unroll
  for (int k2 = 0; k2 < 2; ++k2) {
    int idx = k2 * 256 + tid;
    int t = idx >> 3, ch = idx & 7;
    bf16x8 v = *reinterpret_cast<const bf16x8*>(&ldsT[t][ch * 8]);
    *reinterpret_cast<bf16x8*>(xTb + (size_t)t * C_ + ch * 8) = v;
  }
}

// ---------------------------------------------------------------------------
// Kernel 4: unified projection GEMM (bf16 MFMA).
//   out[o][t] = sum_c Wc[o][c] * xT[t][c],  o in [0,640): Q(64) K(64) V(512)
// grid 256 blocks (1/CU): b = bid&7 (XCD-pinned), t0 = (bid>>3)*128.
// 512 threads = 8 waves; wave w owns o in [80w, 80w+80), all 128 t.
// K-loop kc=32, double-buffered global_load_lds staging: x-slice 8KB,
// W-slice 40KB. A-frag = Wc row (16B), B-frag = xT row (16B), both from LDS.
// Epilogue: LDS-transpose to coalesced 16B stores; bv fused into V.
// ---------------------------------------------------------------------------
__global__ __launch_bounds__(512, 2)
void proj_kernel(const unsigned short* __restrict__ Wc,
                 const unsigned short* __restrict__ xT,
                 const float* __restrict__ bv,
                 unsigned short* __restrict__ Q,
                 unsigned short* __restrict__ Kk,
                 unsigned short* __restrict__ V) {
  __shared__ __align__(16) char smem[98304];  // 96KB: x 2x8KB | W 2x40KB
  const int tid = threadIdx.x;
  const int w = tid >> 6;
  const int lane = tid & 63;
  const int col = lane & 15;
  const int g = lane >> 4;
  const int b = blockIdx.x & 7;
  const int t0 = (blockIdx.x >> 3) * 128;

  const unsigned short* xTb = xT + ((size_t)b * T_ + t0) * C_;

  auto stageX = [&](int bsel, int kc) {
    int off = w * 1024 + lane * 16;
    int tl = off >> 6;
    int cb = off & 63;
    const unsigned short* src = xTb + (size_t)tl * C_ + kc + cb / 2;
    __builtin_amdgcn_global_load_lds(
        (const __attribute__((address_space(1))) unsigned int*)src,
        (__attribute__((address_space(3))) unsigned int*)(smem + bsel * 8192 + off),
        16, 0, 0);
  };
  auto stageW = [&](int bsel, int kc) {
#pragma unroll
    for (int i = 0; i < 5; ++i) {
      int off = i * 8192 + w * 1024 + lane * 16;
      int o = off >> 6;
      int cb = off & 63;
      const unsigned short* src = Wc + (size_t)o * 512 + kc + cb / 2;
      __builtin_amdgcn_global_load_lds(
          (const __attribute__((address_space(1))) unsigned int*)src,
          (__attribute__((address_space(3))) unsigned int*)(smem + 16384 + bsel * 40960 + off),
          16, 0, 0);
    }
  };

  f32x4 acc[5][8];
#pragma unroll
  for (int of = 0; of < 5; ++of)
#pragma unroll
    for (int j = 0; j < 8; ++j) acc[of][j] = (f32x4){0.f, 0.f, 0.f, 0.f};

  stageX(0, 0);
  stageW(0, 0);
  __syncthreads();
  int cur = 0;

  for (int ks = 0; ks < 16; ++ks) {
    int kc = ks * 32;
    if (ks < 15) {
      stageX(cur ^ 1, kc + 32);
      stageW(cur ^ 1, kc + 32);
    }
    bf16x8 af[5], bfr[8];
#pragma unroll
    for (int of = 0; of < 5; ++of) {
      int o = w * 80 + of * 16 + col;
      af[of] = *reinterpret_cast<const bf16x8*>(smem + 16384 + cur * 40960 + o * 64 + g * 16);
    }
#pragma unroll
    for (int j = 0; j < 8; ++j) {
      int tl = 16 * j + col;
      bfr[j] = *reinterpret_cast<const bf16x8*>(smem + cur * 8192 + tl * 64 + g * 16);
    }
#pragma unroll
    for (int of = 0; of < 5; ++of)
#pragma unroll
      for (int j = 0; j < 8; ++j)
        acc[of][j] = __builtin_amdgcn_mfma_f32_16x16x32_bf16(af[of], bfr[j], acc[of][j], 0, 0, 0);
    __syncthreads();  // drains staged loads; buf cur dead, cur^1 ready
    cur ^= 1;
  }

  // ---- epilogue (LDS aliased; all staging dead after final barrier) ----
  unsigned short* qkt = (unsigned short*)smem;                       // [128][136]
  unsigned short* vt = (unsigned short*)(smem + 34816 + w * 4352);   // [16][136]/wave
  unsigned short* Vb = V + (size_t)b * C_ * T_;

#pragma unroll
  for (int of = 0; of < 5; ++of) {
    int o0 = w * 80 + of * 16;
    if (o0 < 128) {
      // Q/K: write transposed into shared [t][d] tile
#pragma unroll
      for (int j = 0; j < 8; ++j)
#pragma unroll
        for (int r = 0; r < 4; ++r)
          qkt[(16 * j + col) * 136 + o0 + g * 4 + r] = f2bf(acc[of][j][r]);
    } else {
      int c0 = o0 - 128;
      float bvr[4];
#pragma unroll
      for (int r = 0; r < 4; ++r) bvr[r] = bv[c0 + g * 4 + r];
#pragma unroll
      for (int j = 0; j < 8; ++j)
#pragma unroll
        for (int r = 0; r < 4; ++r)
          vt[(g * 4 + r) * 136 + 16 * j + col] = f2bf(acc[of][j][r] + bvr[r]);
      // wave-private readback: row o_r (16 lanes x 16B = 128 t)
#pragma unroll
      for (int p = 0; p < 4; ++p) {
        int o_r = p * 4 + g;
        bf16x8 v8 = *reinterpret_cast<const bf16x8*>((char*)vt + o_r * 272 + col * 16);
        *reinterpret_cast<bf16x8*>(Vb + (size_t)(c0 + o_r) * T_ + t0 + col * 8) = v8;
      }
    }
  }
  __syncthreads();
  // cooperative coalesced Q/K store
  unsigned short* Qb = Q + (size_t)b * T_ * DK_;
  unsigned short* Kb = Kk + (size_t)b * T_ * DK_;
#pragma unroll
  for (int k2 = 0; k2 < 2; ++k2) {
    int idx = k2 * 512 + tid;  // 0..1023
    int t = idx >> 3, ch = idx & 7;
    bf16x8 q8 = *reinterpret_cast<const bf16x8*>(&qkt[t * 136 + ch * 8]);
    *reinterpret_cast<bf16x8*>(Qb + (size_t)(t0 + t) * DK_ + ch * 8) = q8;
    bf16x8 k8 = *reinterpret_cast<const bf16x8*>(&qkt[t * 136 + 64 + ch * 8]);
    *reinterpret_cast<bf16x8*>(Kb + (size_t)(t0 + t) * DK_ + ch * 8) = k8;
  }
}

// ---------------------------------------------------------------------------
// Kernel 5: flash attention + residual (unchanged from round 2).
// ---------------------------------------------------------------------------
__global__ __launch_bounds__(512, 2)
void flash_kernel(const unsigned short* __restrict__ Q,
                  const unsigned short* __restrict__ Kk,
                  const unsigned short* __restrict__ V,
                  const float* __restrict__ x, float* __restrict__ out) {
  __shared__ __align__(16) unsigned short v_lds[2][C_ * 64];  // 2 x 64KB
  __shared__ __align__(16) unsigned short p_lds[8][16 * 64];  // 8 x 2KB

  const int tid = threadIdx.x;
  const int w = tid >> 6;
  const int lane = tid & 63;
  const int col = lane & 15;
  const int g = lane >> 4;
  const int bid = blockIdx.x;
  const int b = bid & 7;
  const int t0 = (bid >> 3) * 128;
  const int trow0 = t0 + w * 16;

  const unsigned short* Qb = Q + (size_t)b * T_ * DK_;
  const unsigned short* Kb = Kk + (size_t)b * T_ * DK_;
  const unsigned short* Vb = V + (size_t)b * C_ * T_;

  auto stage = [&](int bsel, int s0) {
#pragma unroll
    for (int i = 0; i < 8; ++i) {
      int o = i * 8192 + tid * 16;
      int c = o >> 7;
      int z = (o & 127) ^ ((c & 7) << 4);
      const unsigned short* src = Vb + (size_t)c * T_ + s0 + (z >> 1);
      void* dst = (char*)(&v_lds[bsel][0]) + i * 8192 + w * 1024;
      __builtin_amdgcn_global_load_lds(
          (const __attribute__((address_space(1))) unsigned int*)src,
          (__attribute__((address_space(3))) unsigned int*)dst, 16, 0, 0);
    }
  };

  bf16x8 qf[2];
  {
    const unsigned short* qrow = Qb + (size_t)(trow0 + col) * DK_ + g * 8;
    qf[0] = *reinterpret_cast<const bf16x8*>(qrow);
    qf[1] = *reinterpret_cast<const bf16x8*>(qrow + 32);
  }

  bf16x8 kf[2][4];
  auto loadK = [&](int s0) {
#pragma unroll
    for (int ks = 0; ks < 2; ++ks)
#pragma unroll
      for (int j = 0; j < 4; ++j)
        kf[ks][j] = *reinterpret_cast<const bf16x8*>(
            Kb + (size_t)(s0 + col + 16 * j) * DK_ + 32 * ks + g * 8);
  };

  float m_r[4], l_r[4];
  f32x4 o_acc[32];
#pragma unroll
  for (int n = 0; n < 32; ++n) o_acc[n] = (f32x4){0.f, 0.f, 0.f, 0.f};
#pragma unroll
  for (int r = 0; r < 4; ++r) { m_r[r] = -1e30f; l_r[r] = 0.f; }

  stage(0, 0);
  loadK(0);
  __syncthreads();
  int cur = 0;

  const float RTHR = 10.0f;

  for (int it = 0; it < T_ / 64; ++it) {
    const int s0 = it * 64;
    if (it + 1 < T_ / 64) stage(cur ^ 1, s0 + 64);

    f32x4 sacc[4];
#pragma unroll
    for (int j = 0; j < 4; ++j) sacc[j] = (f32x4){0.f, 0.f, 0.f, 0.f};
#pragma unroll
    for (int ks = 0; ks < 2; ++ks)
#pragma unroll
      for (int j = 0; j < 4; ++j)
        sacc[j] = __builtin_amdgcn_mfma_f32_16x16x32_bf16(qf[ks], kf[ks][j], sacc[j], 0, 0, 0);

    float mx[4];
#pragma unroll
    for (int r = 0; r < 4; ++r) {
      float m2 = fmaxf(fmaxf(sacc[0][r], sacc[1][r]), fmaxf(sacc[2][r], sacc[3][r]));
      m2 = fmaxf(m2, __shfl_xor(m2, 1));
      m2 = fmaxf(m2, __shfl_xor(m2, 2));
      m2 = fmaxf(m2, __shfl_xor(m2, 4));
      m2 = fmaxf(m2, __shfl_xor(m2, 8));
      mx[r] = m2;
    }
    int ok = (mx[0] <= m_r[0] + RTHR) && (mx[1] <= m_r[1] + RTHR) &&
             (mx[2] <= m_r[2] + RTHR) && (mx[3] <= m_r[3] + RTHR);
    if (!__all(ok)) {
      float scl[4];
#pragma unroll
      for (int r = 0; r < 4; ++r) {
        float mnew = fmaxf(m_r[r], mx[r]);
        scl[r] = exp2f(m_r[r] - mnew);
        m_r[r] = mnew;
        l_r[r] *= scl[r];
      }
#pragma unroll
      for (int n = 0; n < 32; ++n) {
        o_acc[n][0] *= scl[0];
        o_acc[n][1] *= scl[1];
        o_acc[n][2] *= scl[2];
        o_acc[n][3] *= scl[3];
      }
    }
#pragma unroll
    for (int r = 0; r < 4; ++r) {
      float rs = 0.f;
#pragma unroll
      for (int j = 0; j < 4; ++j) {
        float p = exp2f(sacc[j][r] - m_r[r]);
        sacc[j][r] = p;
        rs += p;
      }
      rs += __shfl_xor(rs, 1);
      rs += __shfl_xor(rs, 2);
      rs += __shfl_xor(rs, 4);
      rs += __shfl_xor(rs, 8);
      l_r[r] += rs;
    }

#pragma unroll
    for (int j = 0; j < 4; ++j)
#pragma unroll
      for (int r = 0; r < 4; ++r) {
        int row = g * 4 + r;
        int byteoff = (row * 128 + (16 * j + col) * 2) ^ ((row & 7) << 4);
        *(unsigned short*)((char*)p_lds[w] + byteoff) = f2bf(sacc[j][r]);
      }

#pragma unroll
    for (int ks = 0; ks < 2; ++ks) {
      int bo = (col * 128 + 64 * ks + 16 * g) ^ ((col & 7) << 4);
      bf16x8 pf = *reinterpret_cast<const bf16x8*>((char*)p_lds[w] + bo);
      int zv = (64 * ks + 16 * g) ^ ((col & 7) << 4);
      const char* vb0 = (const char*)v_lds[cur] + col * 128 + zv;
#pragma unroll
      for (int n = 0; n < 32; ++n) {
        bf16x8 vf = *reinterpret_cast<const bf16x8*>(vb0 + n * 2048);
        o_acc[n] = __builtin_amdgcn_mfma_f32_16x16x32_bf16(pf, vf, o_acc[n], 0, 0, 0);
      }
    }

    if (it + 1 < T_ / 64) loadK(s0 + 64);
    __syncthreads();
    cur ^= 1;
  }

  float inv_l[4];
#pragma unroll
  for (int r = 0; r < 4; ++r) inv_l[r] = 1.f / l_r[r];
  const float* xb = x + (size_t)b * C_ * T_;
  float* ob = out + (size_t)b * C_ * T_;
  float* scratch = (float*)((char*)v_lds + (size_t)w * 16384);

#pragma unroll
  for (int ch = 0; ch < 4; ++ch) {
#pragma unroll
    for (int nn = 0; nn < 8; ++nn) {
      int n = ch * 8 + nn;
      int c_local = nn * 16 + col;
#pragma unroll
      for (int r = 0; r < 4; ++r)
        scratch[c_local * 17 + g * 4 + r] = o_acc[n][r] * inv_l[r];
    }
#pragma unroll
    for (int i = 0; i < 32; ++i) {
      int c_local = i * 4 + g;
      float v = scratch[c_local * 17 + col];
      size_t idx = (size_t)(ch * 128 + c_local) * T_ + trow0 + col;
      ob[idx] = v + xb[idx];
    }
  }
}

// ---------------------------------------------------------------------------
extern "C" void kernel_launch(void* const* d_in, const int* in_sizes, int n_in,
                              void* d_out, int out_size, void* d_ws, size_t ws_size,
                              hipStream_t stream) {
  const float* x  = (const float*)d_in[0];
  const float* Wq = (const float*)d_in[1];
  const float* Wk = (const float*)d_in[2];
  const float* Wv = (const float*)d_in[3];
  const float* bv = (const float*)d_in[4];
  const float* u  = (const float*)d_in[5];
  float* out = (float*)d_out;

  char* ws = (char*)d_ws;
  float* sig = (float*)ws;
  unsigned short* Q  = (unsigned short*)(ws + 1024);
  unsigned short* Kk = (unsigned short*)(ws + 1024 + (size_t)4 * 1024 * 1024);
  unsigned short* V  = (unsigned short*)(ws + 1024 + (size_t)8 * 1024 * 1024);
  unsigned short* xT = (unsigned short*)(ws + 1024 + (size_t)40 * 1024 * 1024);
  unsigned short* Wc = (unsigned short*)(ws + 1024 + (size_t)72 * 1024 * 1024);

  sigma_kernel<<<1, 512, 0, stream>>>(Wv, u, sig);
  castw_kernel<<<640, 128, 0, stream>>>(Wq, Wk, Wv, sig, Wc);
  castt_kernel<<<dim3(T_ / 64, C_ / 64, B_), 256, 0, stream>>>(x, xT);
  proj_kernel<<<256, 512, 0, stream>>>(Wc, xT, bv, Q, Kk, V);
  flash_kernel<<<256, 512, 0, stream>>>(Q, Kk, V, x, out);
}

// Round 4
// 364.584 us; speedup vs baseline: 7.5594x; 1.0133x over previous
//
#include <hip/hip_runtime.h>

// ---------------------------------------------------------------------------
// SelfAttention (B=8, C=512, T=4096, DK=64):
//   sigma = spectral norm of Wv (1 power iter); val = (Wv x)/sigma + bv
//   q = Wq x, k = Wk x; attn = softmax(q^T k / 8); out = val @ attn^T + x
// Pipeline:
//   sigma  -> inv_sigma
//   castw  -> Wc[640][512] bf16 = [Wq*log2e/8 ; Wk ; Wv/sigma]
//   castt  -> xT[b][t][c] bf16 (LDS transpose)
//   proj   -> unified MFMA GEMM: Q[t][d], K[t][d], V[c][t] (+bv)
//   flash  -> flash attention, swapped-QK softmax, phase-split PV,
//             raw barriers + counted vmcnt (no per-barrier DMA drain)
// ---------------------------------------------------------------------------

#define B_  8
#define C_  512
#define T_  4096
#define DK_ 64

typedef __bf16 bf16x8 __attribute__((ext_vector_type(8)));
typedef float  f32x4  __attribute__((ext_vector_type(4)));

static __device__ __forceinline__ unsigned short f2bf(float f) {
  unsigned u = __float_as_uint(f);
  u += 0x7fffu + ((u >> 16) & 1u);
  return (unsigned short)(u >> 16);
}

// raw barrier: LDS-visibility wait + barrier, NO vmcnt drain (keeps DMA alive)
#define BAR_LDS() asm volatile("s_waitcnt lgkmcnt(0)\ns_barrier" ::: "memory")

// ---------------------------------------------------------------------------
// Kernel 1: spectral norm -> inv_sigma
// ---------------------------------------------------------------------------
__global__ void sigma_kernel(const float* __restrict__ Wv,
                             const float* __restrict__ u,
                             float* __restrict__ sig) {
  __shared__ float red[512];
  __shared__ float vsh[512];
  __shared__ float snorm;
  int tid = threadIdx.x;  // 512 threads

  vsh[tid] = u[tid];
  __syncthreads();
  float acc = 0.f;
  for (int j = 0; j < 512; ++j) acc += Wv[(size_t)j * 512 + tid] * vsh[j];
  red[tid] = acc * acc;
  __syncthreads();
  for (int s = 256; s >= 1; s >>= 1) {
    if (tid < s) red[tid] += red[tid + s];
    __syncthreads();
  }
  if (tid == 0) snorm = sqrtf(red[0]) + 1e-12f;
  __syncthreads();
  float v = acc / snorm;
  __syncthreads();
  vsh[tid] = v;
  __syncthreads();
  float wacc = 0.f;
  for (int c = 0; c < 512; ++c) wacc += Wv[(size_t)tid * 512 + c] * vsh[c];
  red[tid] = wacc * wacc;
  __syncthreads();
  for (int s = 256; s >= 1; s >>= 1) {
    if (tid < s) red[tid] += red[tid + s];
    __syncthreads();
  }
  if (tid == 0) {
    float ww = red[0];
    float sigma = ww / (sqrtf(ww) + 1e-12f);
    sig[0] = 1.f / sigma;
  }
}

// ---------------------------------------------------------------------------
// Kernel 2: stack + scale weights to bf16: Wc[640][512]
// ---------------------------------------------------------------------------
__global__ __launch_bounds__(128)
void castw_kernel(const float* __restrict__ Wq, const float* __restrict__ Wk,
                  const float* __restrict__ Wv, const float* __restrict__ sig,
                  unsigned short* __restrict__ Wc) {
  int row = blockIdx.x;
  int c = threadIdx.x * 4;
  const float* src;
  float s;
  if (row < 64) {
    src = Wq + (size_t)row * 512;
    s = 1.4426950408889634f / 8.0f;
  } else if (row < 128) {
    src = Wk + (size_t)(row - 64) * 512;
    s = 1.0f;
  } else {
    src = Wv + (size_t)(row - 128) * 512;
    s = sig[0];
  }
  float4 v = *reinterpret_cast<const float4*>(src + c);
  ushort4 o;
  o.x = f2bf(v.x * s);
  o.y = f2bf(v.y * s);
  o.z = f2bf(v.z * s);
  o.w = f2bf(v.w * s);
  *reinterpret_cast<ushort4*>(Wc + (size_t)row * 512 + c) = o;
}

// ---------------------------------------------------------------------------
// Kernel 3: transpose-cast x[b][c][t] f32 -> xT[b][t][c] bf16.
// ---------------------------------------------------------------------------
__global__ __launch_bounds__(256)
void castt_kernel(const float* __restrict__ x, unsigned short* __restrict__ xT) {
  __shared__ __align__(16) unsigned short ldsT[64][72];  // [t][c], +8 pad
  int tid = threadIdx.x;
  int t0 = blockIdx.x * 64, c0 = blockIdx.y * 64, b = blockIdx.z;
  const float* xb = x + ((size_t)b * C_ + c0) * T_ + t0;
#pragma unroll
  for (int k2 = 0; k2 < 4; ++k2) {
    int idx = k2 * 256 + tid;
    int c = idx >> 4, t4 = (idx & 15) * 4;
    float4 v = *reinterpret_cast<const float4*>(xb + (size_t)c * T_ + t4);
    ldsT[t4 + 0][c] = f2bf(v.x);
    ldsT[t4 + 1][c] = f2bf(v.y);
    ldsT[t4 + 2][c] = f2bf(v.z);
    ldsT[t4 + 3][c] = f2bf(v.w);
  }
  __syncthreads();
  unsigned short* xTb = xT + ((size_t)b * T_ + t0) * C_ + c0;
#pragma unroll
  for (int k2 = 0; k2 < 2; ++k2) {
    int idx = k2 * 256 + tid;
    int t = idx >> 3, ch = idx & 7;
    bf16x8 v = *reinterpret_cast<const bf16x8*>(&ldsT[t][ch * 8]);
    *reinterpret_cast<bf16x8*>(xTb + (size_t)t * C_ + ch * 8) = v;
  }
}

// ---------------------------------------------------------------------------
// Kernel 4: unified projection GEMM (bf16 MFMA).  (unchanged, verified)
// ---------------------------------------------------------------------------
__global__ __launch_bounds__(512, 2)
void proj_kernel(const unsigned short* __restrict__ Wc,
                 const unsigned short* __restrict__ xT,
                 const float* __restrict__ bv,
                 unsigned short* __restrict__ Q,
                 unsigned short* __restrict__ Kk,
                 unsigned short* __restrict__ V) {
  __shared__ __align__(16) char smem[98304];  // 96KB: x 2x8KB | W 2x40KB
  const int tid = threadIdx.x;
  const int w = tid >> 6;
  const int lane = tid & 63;
  const int col = lane & 15;
  const int g = lane >> 4;
  const int b = blockIdx.x & 7;
  const int t0 = (blockIdx.x >> 3) * 128;

  const unsigned short* xTb = xT + ((size_t)b * T_ + t0) * C_;

  auto stageX = [&](int bsel, int kc) {
    int off = w * 1024 + lane * 16;
    int tl = off >> 6;
    int cb = off & 63;
    const unsigned short* src = xTb + (size_t)tl * C_ + kc + cb / 2;
    __builtin_amdgcn_global_load_lds(
        (const __attribute__((address_space(1))) unsigned int*)src,
        (__attribute__((address_space(3))) unsigned int*)(smem + bsel * 8192 + off),
        16, 0, 0);
  };
  auto stageW = [&](int bsel, int kc) {
#pragma unroll
    for (int i = 0; i < 5; ++i) {
      int off = i * 8192 + w * 1024 + lane * 16;
      int o = off >> 6;
      int cb = off & 63;
      const unsigned short* src = Wc + (size_t)o * 512 + kc + cb / 2;
      __builtin_amdgcn_global_load_lds(
          (const __attribute__((address_space(1))) unsigned int*)src,
          (__attribute__((address_space(3))) unsigned int*)(smem + 16384 + bsel * 40960 + off),
          16, 0, 0);
    }
  };

  f32x4 acc[5][8];
#pragma unroll
  for (int of = 0; of < 5; ++of)
#pragma unroll
    for (int j = 0; j < 8; ++j) acc[of][j] = (f32x4){0.f, 0.f, 0.f, 0.f};

  stageX(0, 0);
  stageW(0, 0);
  __syncthreads();
  int cur = 0;

  for (int ks = 0; ks < 16; ++ks) {
    int kc = ks * 32;
    if (ks < 15) {
      stageX(cur ^ 1, kc + 32);
      stageW(cur ^ 1, kc + 32);
    }
    bf16x8 af[5], bfr[8];
#pragma unroll
    for (int of = 0; of < 5; ++of) {
      int o = w * 80 + of * 16 + col;
      af[of] = *reinterpret_cast<const bf16x8*>(smem + 16384 + cur * 40960 + o * 64 + g * 16);
    }
#pragma unroll
    for (int j = 0; j < 8; ++j) {
      int tl = 16 * j + col;
      bfr[j] = *reinterpret_cast<const bf16x8*>(smem + cur * 8192 + tl * 64 + g * 16);
    }
#pragma unroll
    for (int of = 0; of < 5; ++of)
#pragma unroll
      for (int j = 0; j < 8; ++j)
        acc[of][j] = __builtin_amdgcn_mfma_f32_16x16x32_bf16(af[of], bfr[j], acc[of][j], 0, 0, 0);
    __syncthreads();
    cur ^= 1;
  }

  unsigned short* qkt = (unsigned short*)smem;                       // [128][136]
  unsigned short* vt = (unsigned short*)(smem + 34816 + w * 4352);   // [16][136]/wave
  unsigned short* Vb = V + (size_t)b * C_ * T_;

#pragma unroll
  for (int of = 0; of < 5; ++of) {
    int o0 = w * 80 + of * 16;
    if (o0 < 128) {
#pragma unroll
      for (int j = 0; j < 8; ++j)
#pragma unroll
        for (int r = 0; r < 4; ++r)
          qkt[(16 * j + col) * 136 + o0 + g * 4 + r] = f2bf(acc[of][j][r]);
    } else {
      int c0 = o0 - 128;
      float bvr[4];
#pragma unroll
      for (int r = 0; r < 4; ++r) bvr[r] = bv[c0 + g * 4 + r];
#pragma unroll
      for (int j = 0; j < 8; ++j)
#pragma unroll
        for (int r = 0; r < 4; ++r)
          vt[(g * 4 + r) * 136 + 16 * j + col] = f2bf(acc[of][j][r] + bvr[r]);
#pragma unroll
      for (int p = 0; p < 4; ++p) {
        int o_r = p * 4 + g;
        bf16x8 v8 = *reinterpret_cast<const bf16x8*>((char*)vt + o_r * 272 + col * 16);
        *reinterpret_cast<bf16x8*>(Vb + (size_t)(c0 + o_r) * T_ + t0 + col * 8) = v8;
      }
    }
  }
  __syncthreads();
  unsigned short* Qb = Q + (size_t)b * T_ * DK_;
  unsigned short* Kb = Kk + (size_t)b * T_ * DK_;
#pragma unroll
  for (int k2 = 0; k2 < 2; ++k2) {
    int idx = k2 * 512 + tid;
    int t = idx >> 3, ch = idx & 7;
    bf16x8 q8 = *reinterpret_cast<const bf16x8*>(&qkt[t * 136 + ch * 8]);
    *reinterpret_cast<bf16x8*>(Qb + (size_t)(t0 + t) * DK_ + ch * 8) = q8;
    bf16x8 k8 = *reinterpret_cast<const bf16x8*>(&qkt[t * 136 + 64 + ch * 8]);
    *reinterpret_cast<bf16x8*>(Kb + (size_t)(t0 + t) * DK_ + ch * 8) = k8;
  }
}

// ---------------------------------------------------------------------------
// Kernel 5: flash attention + residual.
// grid 256 blocks (1/CU): b = bid&7 (XCD-pinned), t0 = (bid>>3)*128.
// 512 threads = 8 waves.
// Phase 1 (per iter): wave w owns q-rows [t0+16w, +16).  S^T = mfma(K, Q)
//   -> per-lane column q=col holds 16 s-values -> max/sum reduce = 2 shfl
//   each; P packed 4-wide -> 4 ds_write_b64 into shared p_lds[128][64]
//   (XOR-swizzled).  Per-wave-local defer-rescale; scale broadcast via LDS
//   only when triggered (flags byte per wave).
// Phase 2: wave w owns channels [64w, 64w+64): reads all of p_lds (16 b128)
//   + its V slice (8 b128) -> 64 MFMA into o_acc[8][4].
// V tile (512x64, 64KB) double-buffered via global_load_lds w/ pre-swizzled
// source.  Raw barriers (lgkmcnt only) + s_waitcnt vmcnt(16) before PV keep
// the next tile's DMA + K loads in flight across both barriers.
// ---------------------------------------------------------------------------
__global__ __launch_bounds__(512, 2)
void flash_kernel(const unsigned short* __restrict__ Q,
                  const unsigned short* __restrict__ Kk,
                  const unsigned short* __restrict__ V,
                  const float* __restrict__ x, float* __restrict__ out) {
  __shared__ __align__(16) unsigned short v_lds[2][C_ * 64];  // 2 x 64KB
  __shared__ __align__(16) unsigned short p_lds[128 * 64];    // 16KB
  __shared__ __align__(16) float scale_lds[8][16];
  __shared__ __align__(16) float l_lds[128];
  __shared__ unsigned long long flags_lds;

  const int tid = threadIdx.x;
  const int w = tid >> 6;
  const int lane = tid & 63;
  const int col = lane & 15;
  const int g = lane >> 4;
  const int b = blockIdx.x & 7;            // batch == XCD slot
  const int t0 = (blockIdx.x >> 3) * 128;
  const int trow0 = t0 + w * 16;

  const unsigned short* Qb = Q + (size_t)b * T_ * DK_;
  const unsigned short* Kb = Kk + (size_t)b * T_ * DK_;
  const unsigned short* Vb = V + (size_t)b * C_ * T_;

  // ---- V tile stage: linear LDS dest, bank-swizzle folded into source ----
  auto stage = [&](int bsel, int s0) {
#pragma unroll
    for (int i = 0; i < 8; ++i) {
      int o = i * 8192 + tid * 16;
      int c = o >> 7;
      int z = (o & 127) ^ ((c & 7) << 4);
      const unsigned short* src = Vb + (size_t)c * T_ + s0 + (z >> 1);
      void* dst = (char*)(&v_lds[bsel][0]) + i * 8192 + w * 1024;
      __builtin_amdgcn_global_load_lds(
          (const __attribute__((address_space(1))) unsigned int*)src,
          (__attribute__((address_space(3))) unsigned int*)dst, 16, 0, 0);
    }
  };

  // Q B-fragments (col = q row), K A-fragments (row = s)
  bf16x8 qf[2];
  {
    const unsigned short* qrow = Qb + (size_t)(trow0 + col) * DK_ + g * 8;
    qf[0] = *reinterpret_cast<const bf16x8*>(qrow);
    qf[1] = *reinterpret_cast<const bf16x8*>(qrow + 32);
  }
  bf16x8 kf[2][4];
  auto loadK = [&](int s0) {
#pragma unroll
    for (int ks = 0; ks < 2; ++ks)
#pragma unroll
      for (int j = 0; j < 4; ++j)
        kf[ks][j] = *reinterpret_cast<const bf16x8*>(
            Kb + (size_t)(s0 + col + 16 * j) * DK_ + 32 * ks + g * 8);
  };

  float m_run = -1e30f, l_run = 0.f;
  f32x4 o_acc[8][4];
#pragma unroll
  for (int qt = 0; qt < 8; ++qt)
#pragma unroll
    for (int ct = 0; ct < 4; ++ct) o_acc[qt][ct] = (f32x4){0.f, 0.f, 0.f, 0.f};

  stage(0, 0);
  loadK(0);
  __syncthreads();  // prologue: full drain, tile 0 + K0 resident
  int cur = 0;

  const float RTHR = 10.0f;  // defer-rescale threshold (log2 domain)
  const int prow = w * 16 + col;               // this lane's q row in p_lds
  const int pswz = (prow & 7) << 4;

  for (int it = 0; it < T_ / 64; ++it) {
    // ---- a: S^T = K Q^T (8 MFMA); lane (col=q) holds s = 16j+4g+r ----
    f32x4 sacc[4];
#pragma unroll
    for (int j = 0; j < 4; ++j) sacc[j] = (f32x4){0.f, 0.f, 0.f, 0.f};
#pragma unroll
    for (int ks = 0; ks < 2; ++ks)
#pragma unroll
      for (int j = 0; j < 4; ++j)
        sacc[j] = __builtin_amdgcn_mfma_f32_16x16x32_bf16(kf[ks][j], qf[ks], sacc[j], 0, 0, 0);

    // ---- b: tile max (lane-local tree + 2 shfl), defer-rescale decision ----
    float t01 = fmaxf(fmaxf(sacc[0][0], sacc[0][1]), fmaxf(sacc[0][2], sacc[0][3]));
    float t23 = fmaxf(fmaxf(sacc[1][0], sacc[1][1]), fmaxf(sacc[1][2], sacc[1][3]));
    float t45 = fmaxf(fmaxf(sacc[2][0], sacc[2][1]), fmaxf(sacc[2][2], sacc[2][3]));
    float t67 = fmaxf(fmaxf(sacc[3][0], sacc[3][1]), fmaxf(sacc[3][2], sacc[3][3]));
    float tm = fmaxf(fmaxf(t01, t23), fmaxf(t45, t67));
    tm = fmaxf(tm, __shfl_xor(tm, 16));
    tm = fmaxf(tm, __shfl_xor(tm, 32));
    int wave_any = __any(tm > m_run + RTHR);
    float sc = 1.0f;
    if (wave_any) {
      float m_new = fmaxf(m_run, tm);
      sc = exp2f(m_run - m_new);
      m_run = m_new;
      if (lane < 16) scale_lds[w][lane] = sc;
    }
    if (lane == 0)
      ((volatile unsigned char*)&flags_lds)[w] = (unsigned char)wave_any;

    BAR_LDS();  // [BAR1] prev PV done (p_lds free); flags/scales visible

    // ---- c: cross-wave o_acc rescale (rare) ----
    unsigned long long fl = flags_lds;
    if (fl) {
#pragma unroll
      for (int qt = 0; qt < 8; ++qt) {
        if ((fl >> (8 * qt)) & 0xffull) {
          f32x4 s4 = *reinterpret_cast<const f32x4*>(&scale_lds[qt][4 * g]);
#pragma unroll
          for (int ct = 0; ct < 4; ++ct) o_acc[qt][ct] *= s4;
        }
      }
    }

    // ---- d: P = exp2(S - m), pack 4-wide, 4x ds_write_b64; l update ----
    float rs = 0.f;
#pragma unroll
    for (int j = 0; j < 4; ++j) {
      float p0 = exp2f(sacc[j][0] - m_run);
      float p1 = exp2f(sacc[j][1] - m_run);
      float p2 = exp2f(sacc[j][2] - m_run);
      float p3 = exp2f(sacc[j][3] - m_run);
      rs += (p0 + p1) + (p2 + p3);
      ushort4 pk = {f2bf(p0), f2bf(p1), f2bf(p2), f2bf(p3)};
      int byteoff = prow * 128 + (((16 * j + 4 * g) * 2) ^ pswz);
      *reinterpret_cast<ushort4*>((char*)p_lds + byteoff) = pk;
    }
    rs += __shfl_xor(rs, 16);
    rs += __shfl_xor(rs, 32);
    l_run = l_run * sc + rs;

    // ---- e/f: prefetch next K (regs) + next V tile (DMA into cur^1) ----
    if (it + 1 < T_ / 64) {
      loadK(64 * (it + 1));
      stage(cur ^ 1, 64 * (it + 1));
    }

    BAR_LDS();  // [BAR2] P visible to all waves; DMA still in flight
    // oldest 8 outstanding = this iter's V tile; allow next K(8)+stage(8)
    asm volatile("s_waitcnt vmcnt(16)" ::: "memory");

    // ---- h: PV  o_acc[qt][ct] += P[16qt..+16] x V[64w+16ct..+16] ----
    const char* vbase = (const char*)v_lds[cur];
#pragma unroll
    for (int ks = 0; ks < 2; ++ks) {
      bf16x8 vf[4];
#pragma unroll
      for (int ct = 0; ct < 4; ++ct) {
        int c_ = 64 * w + 16 * ct + col;
        vf[ct] = *reinterpret_cast<const bf16x8*>(
            vbase + c_ * 128 + ((64 * ks + 16 * g) ^ ((c_ & 7) << 4)));
      }
#pragma unroll
      for (int qt = 0; qt < 8; ++qt) {
        int row = 16 * qt + col;
        bf16x8 pa = *reinterpret_cast<const bf16x8*>(
            (const char*)p_lds + row * 128 + ((64 * ks + 16 * g) ^ ((row & 7) << 4)));
#pragma unroll
        for (int ct = 0; ct < 4; ++ct)
          o_acc[qt][ct] = __builtin_amdgcn_mfma_f32_16x16x32_bf16(pa, vf[ct], o_acc[qt][ct], 0, 0, 0);
      }
    }
    cur ^= 1;
  }

  // ---- epilogue: share l, then direct coalesced f32x4 stores + residual ----
  if (lane < 16) l_lds[w * 16 + lane] = l_run;
  BAR_LDS();

  const float* xb = x + (size_t)b * C_ * T_;
  float* ob = out + (size_t)b * C_ * T_;
#pragma unroll
  for (int qt = 0; qt < 8; ++qt) {
    f32x4 l4 = *reinterpret_cast<const f32x4*>(&l_lds[16 * qt + 4 * g]);
    f32x4 linv;
#pragma unroll
    for (int r = 0; r < 4; ++r) linv[r] = 1.f / l4[r];
#pragma unroll
    for (int ct = 0; ct < 4; ++ct) {
      size_t idx = (size_t)(64 * w + 16 * ct + col) * T_ + t0 + 16 * qt + 4 * g;
      f32x4 xv = *reinterpret_cast<const f32x4*>(xb + idx);
      f32x4 o = o_acc[qt][ct];
#pragma unroll
      for (int r = 0; r < 4; ++r) o[r] = o[r] * linv[r] + xv[r];
      *reinterpret_cast<f32x4*>(ob + idx) = o;
    }
  }
}

// ---------------------------------------------------------------------------
extern "C" void kernel_launch(void* const* d_in, const int* in_sizes, int n_in,
                              void* d_out, int out_size, void* d_ws, size_t ws_size,
                              hipStream_t stream) {
  const float* x  = (const float*)d_in[0];
  const float* Wq = (const float*)d_in[1];
  const float* Wk = (const float*)d_in[2];
  const float* Wv = (const float*)d_in[3];
  const float* bv = (const float*)d_in[4];
  const float* u  = (const float*)d_in[5];
  float* out = (float*)d_out;

  char* ws = (char*)d_ws;
  float* sig = (float*)ws;
  unsigned short* Q  = (unsigned short*)(ws + 1024);
  unsigned short* Kk = (unsigned short*)(ws + 1024 + (size_t)4 * 1024 * 1024);
  unsigned short* V  = (unsigned short*)(ws + 1024 + (size_t)8 * 1024 * 1024);
  unsigned short* xT = (unsigned short*)(ws + 1024 + (size_t)40 * 1024 * 1024);
  unsigned short* Wc = (unsigned short*)(ws + 1024 + (size_t)72 * 1024 * 1024);

  sigma_kernel<<<1, 512, 0, stream>>>(Wv, u, sig);
  castw_kernel<<<640, 128, 0, stream>>>(Wq, Wk, Wv, sig, Wc);
  castt_kernel<<<dim3(T_ / 64, C_ / 64, B_), 256, 0, stream>>>(x, xT);
  proj_kernel<<<256, 512, 0, stream>>>(Wc, xT, bv, Q, Kk, V);
  flash_kernel<<<256, 512, 0, stream>>>(Q, Kk, V, x, out);
}